// Round 2
// baseline (522.761 us; speedup 1.0000x reference)
//
#include <hip/hip_runtime.h>
#include <math.h>

// Problem constants (ODConv 1x1, eval mode)
#define BATCH 32
#define CIN   512
#define COUT  512
#define HW    3136     // 56*56, = 49*64 exactly
#define KNUM  4
#define ADIM  32
#define EPS   1e-5f

// ---------------- workspace layout (bytes) ----------------
static constexpr size_t XT_OFF     = 0;
static constexpr size_t WF_OFF     = 102760448;
static constexpr size_t POOLED_OFF = 119537664;
static constexpr size_t H_OFF      = 119603200;
static constexpr size_t CH_OFF     = 119607296;
static constexpr size_t FLINV_OFF  = 119672832;
static constexpr size_t KN_OFF     = 119738368;
static constexpr size_t BETA_OFF   = 119738880;

typedef __attribute__((ext_vector_type(8))) short short8;   // 8 bf16 = 4 VGPRs (MFMA A/B frag)
typedef __attribute__((ext_vector_type(4))) float float4v;  // MFMA C/D frag

typedef const unsigned int __attribute__((address_space(1)))* gas_ptr;
typedef unsigned int __attribute__((address_space(3)))* lds_ptr;

__device__ __forceinline__ unsigned short f2bf(float f) {
  unsigned int u = __float_as_uint(f);
  u += 0x7FFFu + ((u >> 16) & 1u);   // RNE
  return (unsigned short)(u >> 16);
}

// ---------------- K0: zero the pooled accumulator ----------------
__global__ void zero_f32(float* __restrict__ p, int n) {
  int i = blockIdx.x * blockDim.x + threadIdx.x;
  if (i < n) p[i] = 0.f;
}

// ---------------- K1: x [b][c][p] -> xT bf16 [b][p][c], fused global-avg-pool partials ----
__global__ __launch_bounds__(256) void transpose_pool(
    const float* __restrict__ x, unsigned short* __restrict__ xT,
    float* __restrict__ pooled) {
  __shared__ unsigned short T[64 * 68];   // pitch 68
  const int pb = blockIdx.x * 64;
  const int cb = blockIdx.y * 64;
  const int b  = blockIdx.z;
  const int t  = threadIdx.x;
  const int mp = t & 15;          // p micro index (fast -> coalesced global loads)
  const int mc = t >> 4;          // c micro index
  const int c0 = cb + mc * 4;
  const int p0 = pb + mp * 4;

  const float* xp = x + (size_t)(b * CIN + c0) * HW + p0;
  float a[4][4];
  #pragma unroll
  for (int r = 0; r < 4; ++r) {
    float4 v = *(const float4*)(xp + (size_t)r * HW);
    a[r][0] = v.x; a[r][1] = v.y; a[r][2] = v.z; a[r][3] = v.w;
    float s = v.x + v.y + v.z + v.w;
    #pragma unroll
    for (int off = 8; off > 0; off >>= 1) s += __shfl_down(s, off, 16);
    if (mp == 0) atomicAdd(&pooled[b * CIN + c0 + r], s);
  }
  #pragma unroll
  for (int j = 0; j < 4; ++j) {
    ushort4 w;
    w.x = f2bf(a[0][j]); w.y = f2bf(a[1][j]);
    w.z = f2bf(a[2][j]); w.w = f2bf(a[3][j]);
    *(ushort4*)&T[(mp * 4 + j) * 68 + mc * 4] = w;
  }
  __syncthreads();
  const int pr = t >> 2, cp = t & 3;
  const int base = pr * 68 + cp * 16;
  uint2 r0 = *(uint2*)&T[base + 0];
  uint2 r1 = *(uint2*)&T[base + 4];
  uint2 r2 = *(uint2*)&T[base + 8];
  uint2 r3 = *(uint2*)&T[base + 12];
  unsigned short* dst = xT + (size_t)(b * HW + pb + pr) * CIN + cb + cp * 16;
  *(uint4*)(dst)     = make_uint4(r0.x, r0.y, r1.x, r1.y);
  *(uint4*)(dst + 8) = make_uint4(r2.x, r2.y, r3.x, r3.y);
}

// ---------------- K2a: h = relu(BN(mean(x) @ fc_w^T)), kn = softmax(h @ kn_w^T + kn_b) ----
__global__ __launch_bounds__(256) void attn_h_kn(
    const float* __restrict__ pooled, const float* __restrict__ fc_w,
    const float* __restrict__ abn_g, const float* __restrict__ abn_b,
    const float* __restrict__ abn_m, const float* __restrict__ abn_v,
    const float* __restrict__ kn_w, const float* __restrict__ kn_b,
    float* __restrict__ h_out, float* __restrict__ kn_out) {
  __shared__ float hs[ADIM];
  const int b = blockIdx.x, t = threadIdx.x;
  const int a = t >> 3, part = t & 7;     // 8 lanes per output a
  const float* pr = pooled + b * CIN;
  const float* fr = fc_w + a * CIN;
  float s = 0.f;
  const int cb = part * 64;
  #pragma unroll 8
  for (int c = 0; c < 64; ++c) s += pr[cb + c] * fr[cb + c];
  #pragma unroll
  for (int off = 4; off > 0; off >>= 1) s += __shfl_down(s, off, 8);
  if (part == 0) {
    s *= (1.0f / (float)HW);   // mean
    float vv = (s - abn_m[a]) * (abn_g[a] * rsqrtf(abn_v[a] + EPS)) + abn_b[a];
    vv = fmaxf(vv, 0.f);
    hs[a] = vv;
    h_out[b * ADIM + a] = vv;
  }
  __syncthreads();
  if (t == 0) {
    float lg[KNUM]; float mx = -1e30f;
    for (int k = 0; k < KNUM; ++k) {
      float acc = kn_b[k];
      for (int aa = 0; aa < ADIM; ++aa) acc += hs[aa] * kn_w[k * ADIM + aa];
      lg[k] = acc; mx = fmaxf(mx, acc);
    }
    float ssum = 0.f;
    for (int k = 0; k < KNUM; ++k) { lg[k] = expf(lg[k] - mx); ssum += lg[k]; }
    for (int k = 0; k < KNUM; ++k) kn_out[b * KNUM + k] = lg[k] / ssum;
  }
}

// ---------------- K2b: beta[o] = bn_b - bn_m*inv ----------------
__global__ void beta_kernel(const float* __restrict__ bn_g, const float* __restrict__ bn_b,
                            const float* __restrict__ bn_m, const float* __restrict__ bn_v,
                            float* __restrict__ beta) {
  int o = blockIdx.x * 256 + threadIdx.x;
  if (o < COUT) {
    float inv = bn_g[o] * rsqrtf(bn_v[o] + EPS);
    beta[o] = bn_b[o] - bn_m[o] * inv;
  }
}

// ---------------- K2c: ch = sigmoid(h@ch_w^T+ch_b); flinv = sigmoid(h@fl_w^T+fl_b)*bn_inv ---
__global__ __launch_bounds__(128) void attn_heads(
    const float* __restrict__ h, const float* __restrict__ ch_w, const float* __restrict__ ch_b,
    const float* __restrict__ fl_w, const float* __restrict__ fl_b,
    const float* __restrict__ bn_g, const float* __restrict__ bn_v,
    float* __restrict__ ch_out, float* __restrict__ flinv_out) {
  __shared__ float hs[ADIM];
  const int ck = blockIdx.x, b = blockIdx.y, t = threadIdx.x;
  if (t < ADIM) hs[t] = h[b * ADIM + t];
  __syncthreads();
  if (ck < 4) {
    int c = ck * 128 + t;
    const float* wr = ch_w + c * ADIM;
    float acc = ch_b[c];
    #pragma unroll
    for (int aa = 0; aa < ADIM; ++aa) acc += hs[aa] * wr[aa];
    ch_out[b * CIN + c] = 1.f / (1.f + expf(-acc));
  } else {
    int o = (ck - 4) * 128 + t;
    const float* wr = fl_w + o * ADIM;
    float acc = fl_b[o];
    #pragma unroll
    for (int aa = 0; aa < ADIM; ++aa) acc += hs[aa] * wr[aa];
    float sig = 1.f / (1.f + expf(-acc));
    flinv_out[b * COUT + o] = sig * (bn_g[o] * rsqrtf(bn_v[o] + EPS));
  }
}

// ---------------- K3: Wf[b][o][c] = bf16( flinv[b][o] * ch[b][c] * sum_k kn[b][k]*w[k][o][c] )
__global__ __launch_bounds__(256) void build_wf(
    const float* __restrict__ weight, const float* __restrict__ kn,
    const float* __restrict__ ch, const float* __restrict__ flinv,
    unsigned short* __restrict__ Wf) {
  const int och = blockIdx.x, b = blockIdx.y, t = threadIdx.x;
  const int o0 = och * 16;
  const float k0 = kn[b * KNUM + 0], k1 = kn[b * KNUM + 1];
  const float k2 = kn[b * KNUM + 2], k3 = kn[b * KNUM + 3];
  #pragma unroll
  for (int i = 0; i < 8; ++i) {
    int cell = i * 1024 + t * 4;
    int ol = cell >> 9, c = cell & 511;
    int o = o0 + ol;
    float fi = flinv[b * COUT + o];
    const float* wp = weight + (size_t)o * CIN + c;
    float4 w0 = *(const float4*)(wp);
    float4 w1 = *(const float4*)(wp + 1 * CIN * COUT);
    float4 w2 = *(const float4*)(wp + 2 * CIN * COUT);
    float4 w3 = *(const float4*)(wp + 3 * CIN * COUT);
    float4 cv = *(const float4*)(ch + b * CIN + c);
    ushort4 r;
    r.x = f2bf((k0 * w0.x + k1 * w1.x + k2 * w2.x + k3 * w3.x) * cv.x * fi);
    r.y = f2bf((k0 * w0.y + k1 * w1.y + k2 * w2.y + k3 * w3.y) * cv.y * fi);
    r.z = f2bf((k0 * w0.z + k1 * w1.z + k2 * w2.z + k3 * w3.z) * cv.z * fi);
    r.w = f2bf((k0 * w0.w + k1 * w1.w + k2 * w2.w + k3 * w3.w) * cv.w * fi);
    *(ushort4*)(Wf + (size_t)(b * COUT + o) * CIN + c) = r;
  }
}

// ---------------- K4: y[b][o][p] = sum_c Wf[b][o][c] * xT[b][p][c] + beta[o] ----------------
// 128x128 tile, BK=32, 4 waves (2x2), 4x4 16x16x32 bf16 frags.
// R2 changes: (a) XCD-aware block swizzle: the 4 ot-blocks of one (pt,b) pair run
// back-to-back on the SAME XCD (lin%8 = xcd assumed round-robin) -> xT tile L2 reuse.
// (b) LDS double-buffer, ONE barrier per K-iter; prefetch of kt+1 has a full iter to land.
// (c) XOR bank swizzle on staged col-group -> ds_read_b128 2-way (free) instead of 8-way.
__global__ __launch_bounds__(256) void gemm_kernel(
    const unsigned short* __restrict__ xT, const unsigned short* __restrict__ Wf,
    const float* __restrict__ beta, float* __restrict__ y) {
  __shared__ unsigned short lA[2][128 * 32];  // [o_local][c_local] 2x8KB
  __shared__ unsigned short lB[2][128 * 32];  // [p_local][c_local] 2x8KB

  // grid: 3200 = 8 xcd * 100 pair-groups * 4 ot  (800 (pt,b) pairs total)
  const int lin = blockIdx.x;
  const int xcd = lin & 7;
  const int jj  = lin >> 3;            // temporal order within one XCD
  const int ot  = jj & 3;
  const int pair = xcd * 100 + (jj >> 2);   // 100 pairs per XCD; pt fast within b
  const int b  = pair / 25;
  const int pt = pair % 25;
  const int o0 = ot * 128, p0 = pt * 128;
  const int t = threadIdx.x;
  const int wave = t >> 6, lane = t & 63;
  const int wm = wave & 1, wn = wave >> 1;

  // staging: per wave 2 chunks of 16 rows; lane covers row=lane>>2, 16B col group lane&3,
  // with XOR swizzle by (row>>1)&3 so fragment ds_read_b128 is bank-conflict-free.
  const int lrow = lane >> 2;
  const int csw  = (((lane & 3) ^ ((lrow >> 1) & 3))) * 8;   // swizzled col (shorts)
  const int r0 = (wave * 2 + 0) * 16 + lrow;
  const int r1 = (wave * 2 + 1) * 16 + lrow;

  const unsigned short* Ab = Wf + (size_t)b * COUT * CIN;
  const unsigned short* Bb = xT + (size_t)b * HW * CIN;
  const unsigned short* agp0 = Ab + (size_t)(o0 + r0) * CIN + csw;
  const unsigned short* agp1 = Ab + (size_t)(o0 + r1) * CIN + csw;
  int bp0 = p0 + r0; if (bp0 > HW - 1) bp0 = HW - 1;   // clamp tail tile (stores predicated)
  int bp1 = p0 + r1; if (bp1 > HW - 1) bp1 = HW - 1;
  const unsigned short* bgp0 = Bb + (size_t)bp0 * CIN + csw;
  const unsigned short* bgp1 = Bb + (size_t)bp1 * CIN + csw;

  float4v acc[4][4];
  #pragma unroll
  for (int i = 0; i < 4; ++i)
    #pragma unroll
    for (int j = 0; j < 4; ++j)
      #pragma unroll
      for (int r = 0; r < 4; ++r) acc[i][j][r] = 0.f;

  const int arow = lane & 15;                       // fragment m/n index
  const int kgrp = lane >> 4;                       // logical k group 0..3
  const int ksw  = (kgrp ^ ((arow >> 1) & 3)) * 8;  // swizzled LDS col (shorts)

  // prologue: stage kt=0 into buf 0
  {
    unsigned short* dA0 = &lA[0][(wave * 2 + 0) * 512];
    unsigned short* dA1 = &lA[0][(wave * 2 + 1) * 512];
    unsigned short* dB0 = &lB[0][(wave * 2 + 0) * 512];
    unsigned short* dB1 = &lB[0][(wave * 2 + 1) * 512];
    __builtin_amdgcn_global_load_lds((gas_ptr)(const void*)(agp0), (lds_ptr)(void*)dA0, 16, 0, 0);
    __builtin_amdgcn_global_load_lds((gas_ptr)(const void*)(agp1), (lds_ptr)(void*)dA1, 16, 0, 0);
    __builtin_amdgcn_global_load_lds((gas_ptr)(const void*)(bgp0), (lds_ptr)(void*)dB0, 16, 0, 0);
    __builtin_amdgcn_global_load_lds((gas_ptr)(const void*)(bgp1), (lds_ptr)(void*)dB1, 16, 0, 0);
  }

  int cur = 0;
  for (int kt = 0; kt < CIN / 32; ++kt) {
    __syncthreads();   // drains each wave's own staged loads (vmcnt0) -> buf[cur] complete;
                       // also fences prev iter's ds_reads of buf[cur^1] (consumed pre-barrier)
    if (kt + 1 < CIN / 32) {
      const int c1 = (kt + 1) * 32;
      const int nb = cur ^ 1;
      unsigned short* dA0 = &lA[nb][(wave * 2 + 0) * 512];
      unsigned short* dA1 = &lA[nb][(wave * 2 + 1) * 512];
      unsigned short* dB0 = &lB[nb][(wave * 2 + 0) * 512];
      unsigned short* dB1 = &lB[nb][(wave * 2 + 1) * 512];
      __builtin_amdgcn_global_load_lds((gas_ptr)(const void*)(agp0 + c1), (lds_ptr)(void*)dA0, 16, 0, 0);
      __builtin_amdgcn_global_load_lds((gas_ptr)(const void*)(agp1 + c1), (lds_ptr)(void*)dA1, 16, 0, 0);
      __builtin_amdgcn_global_load_lds((gas_ptr)(const void*)(bgp0 + c1), (lds_ptr)(void*)dB0, 16, 0, 0);
      __builtin_amdgcn_global_load_lds((gas_ptr)(const void*)(bgp1 + c1), (lds_ptr)(void*)dB1, 16, 0, 0);
    }

    short8 af[4], bfr[4];
    #pragma unroll
    for (int i = 0; i < 4; ++i)
      af[i] = *(const short8*)&lA[cur][(wm * 64 + i * 16 + arow) * 32 + ksw];
    #pragma unroll
    for (int j = 0; j < 4; ++j)
      bfr[j] = *(const short8*)&lB[cur][(wn * 64 + j * 16 + arow) * 32 + ksw];
    #pragma unroll
    for (int i = 0; i < 4; ++i)
      #pragma unroll
      for (int j = 0; j < 4; ++j)
        acc[i][j] = __builtin_amdgcn_mfma_f32_16x16x32_bf16(af[i], bfr[j], acc[i][j], 0, 0, 0);
    cur ^= 1;
  }

  // epilogue: C/D map col=lane&15 (p), row=(lane>>4)*4+reg (o)
  const int rowq = (lane >> 4) * 4;
  const int coln = lane & 15;
  #pragma unroll
  for (int i = 0; i < 4; ++i) {
    const int obase = o0 + wm * 64 + i * 16 + rowq;
    float bet[4];
    #pragma unroll
    for (int r = 0; r < 4; ++r) bet[r] = beta[obase + r];
    #pragma unroll
    for (int j = 0; j < 4; ++j) {
      const int p = p0 + wn * 64 + j * 16 + coln;
      if (p < HW) {
        #pragma unroll
        for (int r = 0; r < 4; ++r)
          y[(size_t)(b * COUT + obase + r) * HW + p] = acc[i][j][r] + bet[r];
      }
    }
  }
}

// ---------------- host ----------------
extern "C" void kernel_launch(void* const* d_in, const int* in_sizes, int n_in,
                              void* d_out, int out_size, void* d_ws, size_t ws_size,
                              hipStream_t stream) {
  (void)in_sizes; (void)n_in; (void)out_size; (void)ws_size;
  const float* x     = (const float*)d_in[0];
  const float* fc_w  = (const float*)d_in[1];
  const float* abn_g = (const float*)d_in[2];
  const float* abn_b = (const float*)d_in[3];
  const float* abn_m = (const float*)d_in[4];
  const float* abn_v = (const float*)d_in[5];
  const float* ch_w  = (const float*)d_in[6];
  const float* ch_b  = (const float*)d_in[7];
  const float* fl_w  = (const float*)d_in[8];
  const float* fl_b  = (const float*)d_in[9];
  const float* kn_w  = (const float*)d_in[10];
  const float* kn_b  = (const float*)d_in[11];
  const float* weight= (const float*)d_in[12];
  const float* bn_g  = (const float*)d_in[13];
  const float* bn_b  = (const float*)d_in[14];
  const float* bn_m  = (const float*)d_in[15];
  const float* bn_v  = (const float*)d_in[16];
  float* out = (float*)d_out;

  char* ws = (char*)d_ws;
  unsigned short* xT   = (unsigned short*)(ws + XT_OFF);
  unsigned short* Wf   = (unsigned short*)(ws + WF_OFF);
  float* pooled = (float*)(ws + POOLED_OFF);
  float* h      = (float*)(ws + H_OFF);
  float* ch     = (float*)(ws + CH_OFF);
  float* flinv  = (float*)(ws + FLINV_OFF);
  float* kn     = (float*)(ws + KN_OFF);
  float* beta   = (float*)(ws + BETA_OFF);

  zero_f32<<<64, 256, 0, stream>>>(pooled, BATCH * CIN);
  transpose_pool<<<dim3(HW / 64, CIN / 64, BATCH), 256, 0, stream>>>(x, xT, pooled);
  attn_h_kn<<<BATCH, 256, 0, stream>>>(pooled, fc_w, abn_g, abn_b, abn_m, abn_v,
                                       kn_w, kn_b, h, kn);
  beta_kernel<<<2, 256, 0, stream>>>(bn_g, bn_b, bn_m, bn_v, beta);
  attn_heads<<<dim3(8, BATCH), 128, 0, stream>>>(h, ch_w, ch_b, fl_w, fl_b, bn_g, bn_v,
                                                 ch, flinv);
  build_wf<<<dim3(32, BATCH), 256, 0, stream>>>(weight, kn, ch, flinv, Wf);
  gemm_kernel<<<dim3(3200), 256, 0, stream>>>(xT, Wf, beta, out);
}

// Round 3
// 498.073 us; speedup vs baseline: 1.0496x; 1.0496x over previous
//
#include <hip/hip_runtime.h>
#include <math.h>

// Problem constants (ODConv 1x1, eval mode)
#define BATCH 32
#define CIN   512
#define COUT  512
#define HW    3136     // 56*56 = 49*64
#define KNUM  4
#define ADIM  32
#define EPS   1e-5f

// ---------------- workspace layout (bytes) ----------------
static constexpr size_t XT_OFF    = 0;           // bf16 [B][HW][CIN]  102,760,448
static constexpr size_t WF_OFF    = 102760448;   // bf16 [B][COUT][CIN] 16,777,216
static constexpr size_t PART_OFF  = 119537664;   // f32 [B][49][512]    3,211,264
static constexpr size_t CH_OFF    = 122748928;   // f32 [B][CIN]
static constexpr size_t FLINV_OFF = 122814464;   // f32 [B][COUT]
static constexpr size_t KN_OFF    = 122880000;   // f32 [B][K]

typedef __attribute__((ext_vector_type(8))) short short8;   // 8 bf16 (MFMA A/B frag)
typedef __attribute__((ext_vector_type(4))) float float4v;  // MFMA C/D frag

typedef const unsigned int __attribute__((address_space(1)))* gas_ptr;
typedef unsigned int __attribute__((address_space(3)))* lds_ptr;

__device__ __forceinline__ unsigned short f2bf(float f) {
  unsigned int u = __float_as_uint(f);
  u += 0x7FFFu + ((u >> 16) & 1u);   // RNE
  return (unsigned short)(u >> 16);
}

// ---------------- K1: x [b][c][p] -> xT bf16 [b][p][c], partial pool sums (no atomics) ----
// block = 256c x 64p (4 subtiles of 64c x 64p through one LDS buffer); grid (49, 2, 32).
__global__ __launch_bounds__(256) void transpose_pool(
    const float* __restrict__ x, unsigned short* __restrict__ xT,
    float* __restrict__ part) {
  __shared__ unsigned short T[64 * 68];   // pitch 68
  const int pb    = blockIdx.x * 64;
  const int cbase = blockIdx.y * 256;
  const int b     = blockIdx.z;
  const int t  = threadIdx.x;
  const int mp = t & 15;          // p micro index (fast -> coalesced global loads)
  const int mc = t >> 4;          // c micro index
  const int p0 = pb + mp * 4;
  const int pr = t >> 2, cp = t & 3;

  #pragma unroll
  for (int sub = 0; sub < 4; ++sub) {
    const int cb = cbase + sub * 64;
    const int c0 = cb + mc * 4;
    const float* xp = x + (size_t)(b * CIN + c0) * HW + p0;
    float a[4][4];
    #pragma unroll
    for (int r = 0; r < 4; ++r) {
      float4 v = *(const float4*)(xp + (size_t)r * HW);
      a[r][0] = v.x; a[r][1] = v.y; a[r][2] = v.z; a[r][3] = v.w;
      float s = v.x + v.y + v.z + v.w;
      #pragma unroll
      for (int off = 8; off > 0; off >>= 1) s += __shfl_down(s, off, 16);
      if (mp == 0)
        part[((size_t)b * 49 + blockIdx.x) * 512 + c0 + r] = s;   // partial sum over 64 p
    }
    #pragma unroll
    for (int j = 0; j < 4; ++j) {
      ushort4 w;
      w.x = f2bf(a[0][j]); w.y = f2bf(a[1][j]);
      w.z = f2bf(a[2][j]); w.w = f2bf(a[3][j]);
      *(ushort4*)&T[(mp * 4 + j) * 68 + mc * 4] = w;
    }
    __syncthreads();
    const int base = pr * 68 + cp * 16;
    uint2 r0 = *(uint2*)&T[base + 0];
    uint2 r1 = *(uint2*)&T[base + 4];
    uint2 r2 = *(uint2*)&T[base + 8];
    uint2 r3 = *(uint2*)&T[base + 12];
    unsigned short* dst = xT + (size_t)(b * HW + pb + pr) * CIN + cb + cp * 16;
    *(uint4*)(dst)     = make_uint4(r0.x, r0.y, r1.x, r1.y);
    *(uint4*)(dst + 8) = make_uint4(r2.x, r2.y, r3.x, r3.y);
    __syncthreads();   // T reused next subtile
  }
}

// ---------------- K2: all attention heads fused; grid = (BATCH), 256 thr ----------------
__global__ __launch_bounds__(256) void attn_all(
    const float* __restrict__ part, const float* __restrict__ fc_w,
    const float* __restrict__ abn_g, const float* __restrict__ abn_b,
    const float* __restrict__ abn_m, const float* __restrict__ abn_v,
    const float* __restrict__ kn_w, const float* __restrict__ kn_b,
    const float* __restrict__ ch_w, const float* __restrict__ ch_b,
    const float* __restrict__ fl_w, const float* __restrict__ fl_b,
    const float* __restrict__ bn_g, const float* __restrict__ bn_v,
    float* __restrict__ ch_out, float* __restrict__ flinv_out,
    float* __restrict__ kn_out) {
  __shared__ float pooledS[CIN];
  __shared__ float hs[ADIM];
  const int b = blockIdx.x, t = threadIdx.x;
  // reduce 49 partials -> pooled sums
  #pragma unroll
  for (int idx = t; idx < CIN; idx += 256) {
    float s = 0.f;
    for (int j = 0; j < 49; ++j) s += part[((size_t)b * 49 + j) * 512 + idx];
    pooledS[idx] = s;
  }
  __syncthreads();
  // h = relu(BN(mean @ fc_w^T))
  {
    const int a = t >> 3, pz = t & 7;
    const float* fr = fc_w + a * CIN + pz * 64;
    const float* pp = pooledS + pz * 64;
    float s = 0.f;
    #pragma unroll 8
    for (int c = 0; c < 64; ++c) s += pp[c] * fr[c];
    #pragma unroll
    for (int off = 4; off > 0; off >>= 1) s += __shfl_down(s, off, 8);
    if (pz == 0) {
      s *= (1.0f / (float)HW);
      float vv = (s - abn_m[a]) * (abn_g[a] * rsqrtf(abn_v[a] + EPS)) + abn_b[a];
      hs[a] = fmaxf(vv, 0.f);
    }
  }
  __syncthreads();
  if (t == 0) {   // kn softmax (tiny)
    float lg[KNUM]; float mx = -1e30f;
    for (int k = 0; k < KNUM; ++k) {
      float acc = kn_b[k];
      for (int aa = 0; aa < ADIM; ++aa) acc += hs[aa] * kn_w[k * ADIM + aa];
      lg[k] = acc; mx = fmaxf(mx, acc);
    }
    float ssum = 0.f;
    for (int k = 0; k < KNUM; ++k) { lg[k] = expf(lg[k] - mx); ssum += lg[k]; }
    for (int k = 0; k < KNUM; ++k) kn_out[b * KNUM + k] = lg[k] / ssum;
  }
  // ch & flinv heads
  #pragma unroll
  for (int c = t; c < CIN; c += 256) {
    const float* wr = ch_w + c * ADIM;
    float acc = ch_b[c];
    #pragma unroll
    for (int aa = 0; aa < ADIM; ++aa) acc += hs[aa] * wr[aa];
    ch_out[b * CIN + c] = 1.f / (1.f + expf(-acc));
  }
  #pragma unroll
  for (int o = t; o < COUT; o += 256) {
    const float* wr = fl_w + o * ADIM;
    float acc = fl_b[o];
    #pragma unroll
    for (int aa = 0; aa < ADIM; ++aa) acc += hs[aa] * wr[aa];
    float sig = 1.f / (1.f + expf(-acc));
    flinv_out[b * COUT + o] = sig * (bn_g[o] * rsqrtf(bn_v[o] + EPS));
  }
}

// ---------------- K3: Wf[b][o][c] = bf16( flinv[b][o] * ch[b][c] * sum_k kn[b][k]*w[k][o][c] )
__global__ __launch_bounds__(256) void build_wf(
    const float* __restrict__ weight, const float* __restrict__ kn,
    const float* __restrict__ ch, const float* __restrict__ flinv,
    unsigned short* __restrict__ Wf) {
  const int och = blockIdx.x, b = blockIdx.y, t = threadIdx.x;
  const int o0 = och * 16;
  const float k0 = kn[b * KNUM + 0], k1 = kn[b * KNUM + 1];
  const float k2 = kn[b * KNUM + 2], k3 = kn[b * KNUM + 3];
  #pragma unroll
  for (int i = 0; i < 8; ++i) {
    int cell = i * 1024 + t * 4;
    int ol = cell >> 9, c = cell & 511;
    int o = o0 + ol;
    float fi = flinv[b * COUT + o];
    const float* wp = weight + (size_t)o * CIN + c;
    float4 w0 = *(const float4*)(wp);
    float4 w1 = *(const float4*)(wp + 1 * CIN * COUT);
    float4 w2 = *(const float4*)(wp + 2 * CIN * COUT);
    float4 w3 = *(const float4*)(wp + 3 * CIN * COUT);
    float4 cv = *(const float4*)(ch + b * CIN + c);
    ushort4 r;
    r.x = f2bf((k0 * w0.x + k1 * w1.x + k2 * w2.x + k3 * w3.x) * cv.x * fi);
    r.y = f2bf((k0 * w0.y + k1 * w1.y + k2 * w2.y + k3 * w3.y) * cv.y * fi);
    r.z = f2bf((k0 * w0.z + k1 * w1.z + k2 * w2.z + k3 * w3.z) * cv.z * fi);
    r.w = f2bf((k0 * w0.w + k1 * w1.w + k2 * w2.w + k3 * w3.w) * cv.w * fi);
    *(ushort4*)(Wf + (size_t)(b * COUT + o) * CIN + c) = r;
  }
}

// ---------------- K4: y[b][o][p] = sum_c Wf[b][o][c] * xT[b][p][c] + BN shift ----------------
// 128x128 tile, BK=64, single buffer (32 KB LDS), 2-barrier K-loop with only 8 iterations
// (R1 had 16 barrier-drains; halving them amortizes the vmcnt(0) stall).
// XOR-swizzled LDS columns: source column-group permuted at stage time (dst of
// global_load_lds must stay lane-linear), un-permuted at fragment-read time -> 0 conflicts.
// Grid (ot,pt,b) with ot FASTEST: 4 consecutive blocks share one xT tile -> LLC/L2 reuse.
__global__ __launch_bounds__(256, 4) void gemm_kernel(
    const unsigned short* __restrict__ xT, const unsigned short* __restrict__ Wf,
    const float* __restrict__ bn_g, const float* __restrict__ bn_b,
    const float* __restrict__ bn_m, const float* __restrict__ bn_v,
    float* __restrict__ y) {
  __shared__ unsigned short lA[128 * 64];  // [o_local][c_local(swizzled)] 16 KB
  __shared__ unsigned short lB[128 * 64];  // [p_local][c_local(swizzled)] 16 KB
  const int ot = blockIdx.x, pt = blockIdx.y, b = blockIdx.z;
  const int o0 = ot * 128, p0 = pt * 128;
  const int t = threadIdx.x;
  const int wave = t >> 6, lane = t & 63;
  const int wm = wave & 1, wn = wave >> 1;

  // staging: lane covers (srow = lane>>3 of 8 rows, sgrp = lane&7 of 8 16B-groups);
  // source column-group XOR-permuted by row so LDS slot s holds global group s^(row&7).
  const int srow = lane >> 3;
  const int sgrp = lane & 7;
  const int scol = ((sgrp ^ srow) * 8);              // shorts; row&7 == srow for all chunks

  const unsigned short* Ab = Wf + (size_t)b * COUT * CIN;
  const unsigned short* Bb = xT + (size_t)b * HW * CIN;
  const unsigned short* aSrc[4];
  const unsigned short* bSrc[4];
  #pragma unroll
  for (int q = 0; q < 4; ++q) {
    const int ar = o0 + wave * 32 + q * 8 + srow;
    aSrc[q] = Ab + (size_t)ar * CIN + scol;
    int br = p0 + wave * 32 + q * 8 + srow;
    if (br > HW - 1) br = HW - 1;                    // clamp tail tile (stores predicated)
    bSrc[q] = Bb + (size_t)br * CIN + scol;
  }

  float4v acc[4][4];
  #pragma unroll
  for (int i = 0; i < 4; ++i)
    #pragma unroll
    for (int j = 0; j < 4; ++j)
      #pragma unroll
      for (int r = 0; r < 4; ++r) acc[i][j][r] = 0.f;

  const int arow = lane & 15;                        // fragment m/n index
  const int kgrp = lane >> 4;                        // k quad 0..3
  const int slot0 = ((0 + kgrp) ^ (arow & 7)) * 8;   // un-swizzled LDS col, k-step 0
  const int slot1 = ((4 + kgrp) ^ (arow & 7)) * 8;   // k-step 1

  for (int kt = 0; kt < CIN / 64; ++kt) {
    const int c0 = kt * 64;
    __syncthreads();   // previous iter's ds_reads done before LDS overwrite
    #pragma unroll
    for (int q = 0; q < 4; ++q) {
      __builtin_amdgcn_global_load_lds((gas_ptr)(const void*)(aSrc[q] + c0),
          (lds_ptr)(void*)&lA[(wave * 32 + q * 8) * 64], 16, 0, 0);
      __builtin_amdgcn_global_load_lds((gas_ptr)(const void*)(bSrc[q] + c0),
          (lds_ptr)(void*)&lB[(wave * 32 + q * 8) * 64], 16, 0, 0);
    }
    __syncthreads();   // vmcnt(0) drain: staging visible

    #pragma unroll
    for (int ks = 0; ks < 2; ++ks) {
      const int sl = ks ? slot1 : slot0;
      short8 af[4], bfr[4];
      #pragma unroll
      for (int i = 0; i < 4; ++i)
        af[i] = *(const short8*)&lA[(wm * 64 + i * 16 + arow) * 64 + sl];
      #pragma unroll
      for (int j = 0; j < 4; ++j)
        bfr[j] = *(const short8*)&lB[(wn * 64 + j * 16 + arow) * 64 + sl];
      #pragma unroll
      for (int i = 0; i < 4; ++i)
        #pragma unroll
        for (int j = 0; j < 4; ++j)
          acc[i][j] = __builtin_amdgcn_mfma_f32_16x16x32_bf16(af[i], bfr[j], acc[i][j], 0, 0, 0);
    }
  }

  // epilogue: C/D map col=lane&15 (p), row=(lane>>4)*4+reg (o); BN folded inline
  const int rowq = (lane >> 4) * 4;
  const int coln = lane & 15;
  #pragma unroll
  for (int i = 0; i < 4; ++i) {
    const int obase = o0 + wm * 64 + i * 16 + rowq;
    float bet[4];
    #pragma unroll
    for (int r = 0; r < 4; ++r) {
      const int o = obase + r;
      const float inv = bn_g[o] * rsqrtf(bn_v[o] + EPS);
      bet[r] = bn_b[o] - bn_m[o] * inv;
    }
    #pragma unroll
    for (int j = 0; j < 4; ++j) {
      const int p = p0 + wn * 64 + j * 16 + coln;
      if (p < HW) {
        #pragma unroll
        for (int r = 0; r < 4; ++r)
          y[(size_t)(b * COUT + obase + r) * HW + p] = acc[i][j][r] + bet[r];
      }
    }
  }
}

// ---------------- host ----------------
extern "C" void kernel_launch(void* const* d_in, const int* in_sizes, int n_in,
                              void* d_out, int out_size, void* d_ws, size_t ws_size,
                              hipStream_t stream) {
  (void)in_sizes; (void)n_in; (void)out_size; (void)ws_size;
  const float* x     = (const float*)d_in[0];
  const float* fc_w  = (const float*)d_in[1];
  const float* abn_g = (const float*)d_in[2];
  const float* abn_b = (const float*)d_in[3];
  const float* abn_m = (const float*)d_in[4];
  const float* abn_v = (const float*)d_in[5];
  const float* ch_w  = (const float*)d_in[6];
  const float* ch_b  = (const float*)d_in[7];
  const float* fl_w  = (const float*)d_in[8];
  const float* fl_b  = (const float*)d_in[9];
  const float* kn_w  = (const float*)d_in[10];
  const float* kn_b  = (const float*)d_in[11];
  const float* weight= (const float*)d_in[12];
  const float* bn_g  = (const float*)d_in[13];
  const float* bn_b  = (const float*)d_in[14];
  const float* bn_m  = (const float*)d_in[15];
  const float* bn_v  = (const float*)d_in[16];
  float* out = (float*)d_out;

  char* ws = (char*)d_ws;
  unsigned short* xT = (unsigned short*)(ws + XT_OFF);
  unsigned short* Wf = (unsigned short*)(ws + WF_OFF);
  float* part  = (float*)(ws + PART_OFF);
  float* ch    = (float*)(ws + CH_OFF);
  float* flinv = (float*)(ws + FLINV_OFF);
  float* kn    = (float*)(ws + KN_OFF);

  transpose_pool<<<dim3(49, 2, BATCH), 256, 0, stream>>>(x, xT, part);
  attn_all<<<BATCH, 256, 0, stream>>>(part, fc_w, abn_g, abn_b, abn_m, abn_v,
                                      kn_w, kn_b, ch_w, ch_b, fl_w, fl_b,
                                      bn_g, bn_v, ch, flinv, kn);
  build_wf<<<dim3(32, BATCH), 256, 0, stream>>>(weight, kn, ch, flinv, Wf);
  gemm_kernel<<<dim3(4, 25, BATCH), 256, 0, stream>>>(xT, Wf, bn_g, bn_b, bn_m, bn_v, out);
}